// Round 7
// baseline (292.377 us; speedup 1.0000x reference)
//
#include <hip/hip_runtime.h>
#include <stdint.h>

// INSTRUMENTATION ROUND: two kernels, each repeating its full pass kRep times
// (accumulate, scale by 1/kRep -- identical numerics) so they exceed the 77us
// fill dispatches and appear in the rocprof top-5 with real counters.
//   A: faithful R6 structure (hi/lo split, 12 MFMA/panel, 256 thr) -> d_out
//   B: candidate (pure bf16-RNE, 4 MFMA/panel, 512 thr = 8 waves) -> d_ws
// B's output goes to scratch; correctness is carried by A.

constexpr int kB   = 512;
constexpr int kL   = 2048;
constexpr int kD   = 32;
constexpr int kOut = 528;
constexpr int kPan = 32;
constexpr int kRep = 3;

typedef __attribute__((ext_vector_type(8))) short bfrag;
typedef __attribute__((ext_vector_type(4))) float f4acc;
union FragU { uint32_t u[4]; bfrag f; };

// ---------------------------------------------------------------- kernel A --
constexpr int kTwA = 512;           // t per wave (4 waves)
constexpr int kNPA = kTwA / kPan;   // 16 panels

__global__ __launch_bounds__(256, 2)
void logsig_instrA(const float* __restrict__ x, float* __restrict__ out) {
    __shared__ float sW[4][kD * kD];
    __shared__ float sM[kD * kD];
    __shared__ float sx0[kD], sL1[kD];

    const int b    = blockIdx.x;
    const int tid  = threadIdx.x;
    const int wave = tid >> 6;
    const int lane = tid & 63;
    const int m    = lane & 15;
    const int q    = lane >> 4;

    const float* __restrict__ xb = x + (size_t)b * (kL * kD);
    const int t0  = wave * kTwA;
    const int rb0 = t0 + q * 8;
    const uint32_t* __restrict__ base =
        (const uint32_t*)xb + (size_t)rb0 * kD + m;

    f4acc acc[4];
    #pragma unroll
    for (int t = 0; t < 4; ++t)
        #pragma unroll
        for (int e = 0; e < 4; ++e) acc[t][e] = 0.0f;

    auto load_panel = [&](int p, uint32_t* e0, uint32_t* e1) {
        const uint32_t* bp = base + (size_t)p * kPan * kD;
        #pragma unroll
        for (int j = 0; j < 8; ++j) {
            e0[j] = bp[j * kD];
            e1[j] = bp[j * kD + 16];
        }
        const int rb = rb0 + p * kPan;
        const int ex = (rb + 8 <= kL - 1 ? 8 : (kL - 1) - rb) * kD;
        e0[8] = bp[ex];
        e1[8] = bp[ex + 16];
    };

    auto make_frags = [&](const uint32_t* e, FragU& AH, FragU& AL,
                          FragU& BH, FragU& BL) {
        uint32_t l[9];
        #pragma unroll
        for (int j = 0; j < 9; ++j) {
            const uint32_t fh = e[j] & 0xffff0000u;
            const float r = __builtin_bit_cast(float, e[j])
                          - __builtin_bit_cast(float, fh);
            l[j] = __builtin_bit_cast(uint32_t, r);
        }
        #pragma unroll
        for (int d = 0; d < 4; ++d) {
            AH.u[d] = __builtin_amdgcn_perm(e[2*d+1], e[2*d],   0x07060302u);
            AL.u[d] = __builtin_amdgcn_perm(l[2*d+1], l[2*d],   0x07060302u);
            BH.u[d] = __builtin_amdgcn_perm(e[2*d+2], e[2*d+1], 0x07060302u);
            BL.u[d] = __builtin_amdgcn_perm(l[2*d+2], l[2*d+1], 0x07060302u);
        }
    };

    #pragma unroll 1
    for (int rep = 0; rep < kRep; ++rep) {
        uint32_t buf[2][2][9];
        load_panel(0, buf[0][0], buf[0][1]);
        #pragma unroll 2
        for (int p = 0; p < kNPA; ++p) {
            const int cu = p & 1, nx = cu ^ 1;
            if (p + 1 < kNPA) load_panel(p + 1, buf[nx][0], buf[nx][1]);
            FragU A0H, A0L, B0H, B0L, A1H, A1L, B1H, B1L;
            make_frags(buf[cu][0], A0H, A0L, B0H, B0L);
            make_frags(buf[cu][1], A1H, A1L, B1H, B1L);
            acc[0] = __builtin_amdgcn_mfma_f32_16x16x32_bf16(A0H.f, B0H.f, acc[0], 0, 0, 0);
            acc[0] = __builtin_amdgcn_mfma_f32_16x16x32_bf16(A0H.f, B0L.f, acc[0], 0, 0, 0);
            acc[0] = __builtin_amdgcn_mfma_f32_16x16x32_bf16(A0L.f, B0H.f, acc[0], 0, 0, 0);
            acc[1] = __builtin_amdgcn_mfma_f32_16x16x32_bf16(A0H.f, B1H.f, acc[1], 0, 0, 0);
            acc[1] = __builtin_amdgcn_mfma_f32_16x16x32_bf16(A0H.f, B1L.f, acc[1], 0, 0, 0);
            acc[1] = __builtin_amdgcn_mfma_f32_16x16x32_bf16(A0L.f, B1H.f, acc[1], 0, 0, 0);
            acc[2] = __builtin_amdgcn_mfma_f32_16x16x32_bf16(A1H.f, B0H.f, acc[2], 0, 0, 0);
            acc[2] = __builtin_amdgcn_mfma_f32_16x16x32_bf16(A1H.f, B0L.f, acc[2], 0, 0, 0);
            acc[2] = __builtin_amdgcn_mfma_f32_16x16x32_bf16(A1L.f, B0H.f, acc[2], 0, 0, 0);
            acc[3] = __builtin_amdgcn_mfma_f32_16x16x32_bf16(A1H.f, B1H.f, acc[3], 0, 0, 0);
            acc[3] = __builtin_amdgcn_mfma_f32_16x16x32_bf16(A1H.f, B1L.f, acc[3], 0, 0, 0);
            acc[3] = __builtin_amdgcn_mfma_f32_16x16x32_bf16(A1L.f, B1H.f, acc[3], 0, 0, 0);
        }
    }

    const float scale = 1.0f / (float)kRep;
    #pragma unroll
    for (int t = 0; t < 4; ++t) {
        const int tr = t >> 1, tc = t & 1;
        #pragma unroll
        for (int e = 0; e < 4; ++e) {
            const int row = 16 * tr + q * 4 + e;
            const int col = 16 * tc + m;
            sW[wave][row * kD + col] = acc[t][e] * scale;
        }
    }
    if (tid < kD) {
        const float x0v = xb[tid];
        const float xev = xb[(size_t)(kL - 1) * kD + tid];
        sx0[tid] = x0v;
        sL1[tid] = xev - x0v;
    }
    __syncthreads();
    for (int c = tid; c < kD * kD; c += 256)
        sM[c] = sW[0][c] + sW[1][c] + sW[2][c] + sW[3][c];
    __syncthreads();

    float* ob = out + (size_t)b * kOut;
    for (int o = tid; o < kOut; o += 256) {
        if (o < 32) {
            ob[o] = sL1[o];
        } else {
            int p = o - 32, i = 0;
            while (p >= 31 - i) { p -= 31 - i; ++i; }
            const int j = i + 1 + p;
            ob[o] = 0.5f * (sM[i * kD + j] - sM[j * kD + i]
                            + sx0[j] * sL1[i] - sx0[i] * sL1[j]);
        }
    }
}

// ---------------------------------------------------------------- kernel B --
// pure bf16 RNE (no lo-split): est. absmax ~0.3 << 2.94 threshold.
// 512 threads = 8 waves, 256 t/wave, 4 MFMA/panel. Output -> d_ws (scratch).
constexpr int kTwB = 256;
constexpr int kNPB = kTwB / kPan;   // 8 panels

__device__ __forceinline__ uint32_t rne_hi(uint32_t fb) {
    return (fb + 0x7fffu + ((fb >> 16) & 1u)) & 0xffff0000u;
}

__global__ __launch_bounds__(512, 2)
void logsig_instrB(const float* __restrict__ x, float* __restrict__ out) {
    __shared__ float sW[8][kD * kD];
    __shared__ float sM[kD * kD];
    __shared__ float sx0[kD], sL1[kD];

    const int b    = blockIdx.x;
    const int tid  = threadIdx.x;
    const int wave = tid >> 6;
    const int lane = tid & 63;
    const int m    = lane & 15;
    const int q    = lane >> 4;

    const float* __restrict__ xb = x + (size_t)b * (kL * kD);
    const int t0  = wave * kTwB;
    const int rb0 = t0 + q * 8;
    const uint32_t* __restrict__ base =
        (const uint32_t*)xb + (size_t)rb0 * kD + m;

    f4acc acc[4];
    #pragma unroll
    for (int t = 0; t < 4; ++t)
        #pragma unroll
        for (int e = 0; e < 4; ++e) acc[t][e] = 0.0f;

    auto load_panel = [&](int p, uint32_t* e0, uint32_t* e1) {
        const uint32_t* bp = base + (size_t)p * kPan * kD;
        #pragma unroll
        for (int j = 0; j < 8; ++j) {
            e0[j] = bp[j * kD];
            e1[j] = bp[j * kD + 16];
        }
        const int rb = rb0 + p * kPan;
        const int ex = (rb + 8 <= kL - 1 ? 8 : (kL - 1) - rb) * kD;
        e0[8] = bp[ex];
        e1[8] = bp[ex + 16];
    };

    auto make_frags = [&](const uint32_t* e, FragU& AH, FragU& BH) {
        uint32_t h[9];
        #pragma unroll
        for (int j = 0; j < 9; ++j) h[j] = rne_hi(e[j]);
        #pragma unroll
        for (int d = 0; d < 4; ++d) {
            AH.u[d] = __builtin_amdgcn_perm(h[2*d+1], h[2*d],   0x07060302u);
            BH.u[d] = __builtin_amdgcn_perm(h[2*d+2], h[2*d+1], 0x07060302u);
        }
    };

    #pragma unroll 1
    for (int rep = 0; rep < kRep; ++rep) {
        uint32_t buf[2][2][9];
        load_panel(0, buf[0][0], buf[0][1]);
        #pragma unroll 2
        for (int p = 0; p < kNPB; ++p) {
            const int cu = p & 1, nx = cu ^ 1;
            if (p + 1 < kNPB) load_panel(p + 1, buf[nx][0], buf[nx][1]);
            FragU A0, B0, A1, B1;
            make_frags(buf[cu][0], A0, B0);
            make_frags(buf[cu][1], A1, B1);
            acc[0] = __builtin_amdgcn_mfma_f32_16x16x32_bf16(A0.f, B0.f, acc[0], 0, 0, 0);
            acc[1] = __builtin_amdgcn_mfma_f32_16x16x32_bf16(A0.f, B1.f, acc[1], 0, 0, 0);
            acc[2] = __builtin_amdgcn_mfma_f32_16x16x32_bf16(A1.f, B0.f, acc[2], 0, 0, 0);
            acc[3] = __builtin_amdgcn_mfma_f32_16x16x32_bf16(A1.f, B1.f, acc[3], 0, 0, 0);
        }
    }

    const float scale = 1.0f / (float)kRep;
    #pragma unroll
    for (int t = 0; t < 4; ++t) {
        const int tr = t >> 1, tc = t & 1;
        #pragma unroll
        for (int e = 0; e < 4; ++e) {
            const int row = 16 * tr + q * 4 + e;
            const int col = 16 * tc + m;
            sW[wave][row * kD + col] = acc[t][e] * scale;
        }
    }
    if (tid < kD) {
        const float x0v = xb[tid];
        const float xev = xb[(size_t)(kL - 1) * kD + tid];
        sx0[tid] = x0v;
        sL1[tid] = xev - x0v;
    }
    __syncthreads();
    for (int c = tid; c < kD * kD; c += 512)
        sM[c] = sW[0][c] + sW[1][c] + sW[2][c] + sW[3][c]
              + sW[4][c] + sW[5][c] + sW[6][c] + sW[7][c];
    __syncthreads();

    float* ob = out + (size_t)b * kOut;
    for (int o = tid; o < kOut; o += 512) {
        if (o < 32) {
            ob[o] = sL1[o];
        } else {
            int p = o - 32, i = 0;
            while (p >= 31 - i) { p -= 31 - i; ++i; }
            const int j = i + 1 + p;
            ob[o] = 0.5f * (sM[i * kD + j] - sM[j * kD + i]
                            + sx0[j] * sL1[i] - sx0[i] * sL1[j]);
        }
    }
}

extern "C" void kernel_launch(void* const* d_in, const int* in_sizes, int n_in,
                              void* d_out, int out_size, void* d_ws, size_t ws_size,
                              hipStream_t stream) {
    const float* x = (const float*)d_in[0];
    logsig_instrA<<<dim3(kB), dim3(256), 0, stream>>>(x, (float*)d_out);
    logsig_instrB<<<dim3(kB), dim3(512), 0, stream>>>(x, (float*)d_ws);
}

// Round 8
// 197.360 us; speedup vs baseline: 1.4814x; 1.4814x over previous
//
#include <hip/hip_runtime.h>
#include <stdint.h>

// LogSig depth-2 via MFMA, LDS-free main loop, HIGH OCCUPANCY:
//   grid 2048 = 4 chunk-blocks per batch x 256 thr; 4 waves/block,
//   128 t/wave = 4 K-panels. launch_bounds(256,8) (VGPR cap 64; loop
//   measured at 52) + 16.3 KB LDS -> 8 blocks/CU = 32 waves/CU (100% cap).
//   R7 counters: 19.5% occupancy, MfmaUtil 7.6%, VALUBusy 15% -> latency-
//   bound; wave count is the knob.
// Math (verified R4-R7): M = sum_t x[t] (x) x[t+1] (K=2047; end-clamped halo
//   adds symmetric x[2047](x)x[2047], cancels in antisymmetrization),
//   A = 0.5*(M - M^T - x0 (x) L1 + L1 (x) x0), L1 = x[2047]-x[0].
//   fp32 -> truncation hi/lo split, M ~= aH*bH + aH*bL + aL*bH (absmax 0.5).
// Areas are linear in M -> chunk blocks atomicAdd into pre-zeroed out.

constexpr int kB   = 512;
constexpr int kL   = 2048;
constexpr int kD   = 32;
constexpr int kOut = 528;          // 32 level1 + 496 areas
constexpr int kPan = 32;           // timesteps per K=32 MFMA panel
constexpr int kTw  = 128;          // timesteps per wave
constexpr int kNP  = kTw / kPan;   // 4 panels per wave

typedef __attribute__((ext_vector_type(8))) short bfrag;
typedef __attribute__((ext_vector_type(4))) float f4acc;
union FragU { uint32_t u[4]; bfrag f; };

__global__ __launch_bounds__(256, 8)
void logsig_mfma(const float* __restrict__ x, float* __restrict__ out) {
    __shared__ float sW[4][kD * kD];   // per-wave partial M (16 KB), reduced in place
    __shared__ float sx0[kD], sL1[kD];

    const int b     = blockIdx.x >> 2;
    const int chunk = blockIdx.x & 3;
    const int tid   = threadIdx.x;
    const int wave  = tid >> 6;
    const int lane  = tid & 63;
    const int m     = lane & 15;   // MFMA m/n index
    const int q     = lane >> 4;   // quad: k = q*8 + j

    const float* __restrict__ xb = x + (size_t)b * (kL * kD);
    const int t0  = chunk * (4 * kTw) + wave * kTw;
    const int rb0 = t0 + q * 8;

    const uint32_t* __restrict__ base =
        (const uint32_t*)xb + (size_t)rb0 * kD + m;

    f4acc acc[4];
    #pragma unroll
    for (int t = 0; t < 4; ++t)
        #pragma unroll
        for (int e = 0; e < 4; ++e) acc[t][e] = 0.0f;

    // 9-element chains (j=0..7 + halo for the B shift), both channel halves
    auto load_panel = [&](int p, uint32_t* e0, uint32_t* e1) {
        const uint32_t* bp = base + (size_t)p * kPan * kD;
        #pragma unroll
        for (int j = 0; j < 8; ++j) {
            e0[j] = bp[j * kD];        // x[rb+j][m]
            e1[j] = bp[j * kD + 16];   // x[rb+j][m+16]
        }
        const int rb = rb0 + p * kPan;
        const int ex = (rb + 8 <= kL - 1 ? 8 : (kL - 1) - rb) * kD;  // end clamp
        e0[8] = bp[ex];
        e1[8] = bp[ex + 16];
    };

    // truncation hi/lo split + perm-pack: A pairs (j,j+1), B pairs (j+1,j+2)
    auto make_frags = [&](const uint32_t* e, FragU& AH, FragU& AL,
                          FragU& BH, FragU& BL) {
        uint32_t l[9];
        #pragma unroll
        for (int j = 0; j < 9; ++j) {
            const uint32_t fh = e[j] & 0xffff0000u;
            const float r = __builtin_bit_cast(float, e[j])
                          - __builtin_bit_cast(float, fh);
            l[j] = __builtin_bit_cast(uint32_t, r);
        }
        #pragma unroll
        for (int d = 0; d < 4; ++d) {
            AH.u[d] = __builtin_amdgcn_perm(e[2*d+1], e[2*d],   0x07060302u);
            AL.u[d] = __builtin_amdgcn_perm(l[2*d+1], l[2*d],   0x07060302u);
            BH.u[d] = __builtin_amdgcn_perm(e[2*d+2], e[2*d+1], 0x07060302u);
            BL.u[d] = __builtin_amdgcn_perm(l[2*d+2], l[2*d+1], 0x07060302u);
        }
    };

    uint32_t buf[2][2][9];   // [parity][half][chain]
    load_panel(0, buf[0][0], buf[0][1]);

    #pragma unroll
    for (int p = 0; p < kNP; ++p) {
        const int cu = p & 1, nx = cu ^ 1;
        if (p + 1 < kNP) load_panel(p + 1, buf[nx][0], buf[nx][1]);

        FragU A0H, A0L, B0H, B0L, A1H, A1L, B1H, B1L;
        make_frags(buf[cu][0], A0H, A0L, B0H, B0L);
        make_frags(buf[cu][1], A1H, A1L, B1H, B1L);

        acc[0] = __builtin_amdgcn_mfma_f32_16x16x32_bf16(A0H.f, B0H.f, acc[0], 0, 0, 0);
        acc[0] = __builtin_amdgcn_mfma_f32_16x16x32_bf16(A0H.f, B0L.f, acc[0], 0, 0, 0);
        acc[0] = __builtin_amdgcn_mfma_f32_16x16x32_bf16(A0L.f, B0H.f, acc[0], 0, 0, 0);
        acc[1] = __builtin_amdgcn_mfma_f32_16x16x32_bf16(A0H.f, B1H.f, acc[1], 0, 0, 0);
        acc[1] = __builtin_amdgcn_mfma_f32_16x16x32_bf16(A0H.f, B1L.f, acc[1], 0, 0, 0);
        acc[1] = __builtin_amdgcn_mfma_f32_16x16x32_bf16(A0L.f, B1H.f, acc[1], 0, 0, 0);
        acc[2] = __builtin_amdgcn_mfma_f32_16x16x32_bf16(A1H.f, B0H.f, acc[2], 0, 0, 0);
        acc[2] = __builtin_amdgcn_mfma_f32_16x16x32_bf16(A1H.f, B0L.f, acc[2], 0, 0, 0);
        acc[2] = __builtin_amdgcn_mfma_f32_16x16x32_bf16(A1L.f, B0H.f, acc[2], 0, 0, 0);
        acc[3] = __builtin_amdgcn_mfma_f32_16x16x32_bf16(A1H.f, B1H.f, acc[3], 0, 0, 0);
        acc[3] = __builtin_amdgcn_mfma_f32_16x16x32_bf16(A1H.f, B1L.f, acc[3], 0, 0, 0);
        acc[3] = __builtin_amdgcn_mfma_f32_16x16x32_bf16(A1L.f, B1H.f, acc[3], 0, 0, 0);
    }

    // ---- epilogue ----
    #pragma unroll
    for (int t = 0; t < 4; ++t) {
        const int tr = t >> 1, tc = t & 1;
        #pragma unroll
        for (int e = 0; e < 4; ++e) {
            const int row = 16 * tr + q * 4 + e;   // C/D layout (m89-verified)
            const int col = 16 * tc + m;
            sW[wave][row * kD + col] = acc[t][e];
        }
    }
    if (tid < kD) {
        const float x0v = xb[tid];
        const float xev = xb[(size_t)(kL - 1) * kD + tid];
        sx0[tid] = x0v;
        sL1[tid] = xev - x0v;
    }
    __syncthreads();

    for (int c = tid; c < kD * kD; c += 256)
        sW[0][c] += sW[1][c] + sW[2][c] + sW[3][c];
    __syncthreads();

    float* ob = out + (size_t)b * kOut;
    for (int o = tid; o < kOut; o += 256) {
        if (o < 32) {
            if (chunk == 0) ob[o] = sL1[o];        // level1, single writer
        } else {
            int p = o - 32, i = 0;                 // triu pair index -> (i,j)
            while (p >= 31 - i) { p -= 31 - i; ++i; }
            const int j = i + 1 + p;
            float v = 0.5f * (sW[0][i * kD + j] - sW[0][j * kD + i]);
            if (chunk == 0)
                v += 0.5f * (sx0[j] * sL1[i] - sx0[i] * sL1[j]);
            atomicAdd(ob + o, v);
        }
    }
}

extern "C" void kernel_launch(void* const* d_in, const int* in_sizes, int n_in,
                              void* d_out, int out_size, void* d_ws, size_t ws_size,
                              hipStream_t stream) {
    const float* x = (const float*)d_in[0];
    float* out = (float*)d_out;
    hipMemsetAsync(out, 0, (size_t)out_size * sizeof(float), stream);
    logsig_mfma<<<dim3(kB * 4), dim3(256), 0, stream>>>(x, out);
}

// Round 9
// 191.845 us; speedup vs baseline: 1.5240x; 1.0287x over previous
//
#include <hip/hip_runtime.h>
#include <stdint.h>

// LogSig depth-2 via MFMA with m97-style async staging.
//   M = sum_t x[t] (x) x[t+1]  (K=2047; clamped end row adds a symmetric
//   x[2047](x)x[2047] term that cancels in antisymmetrization)
//   A = 0.5*(M - M^T - x0 (x) L1 + L1 (x) x0),  L1 = x[2047]-x[0]
//   fp32 -> truncation hi/lo split, M ~= aH*bH + aH*bL + aL*bH (absmax ~0.5).
//
// R8 lesson: 4-B gather loads cap at ~2.1 TB/s (half-line MSHR waste).
// Fix: stage 32-row panels (4 KB) per wave via global_load_lds dwordx4 --
// 1 KB contiguous per instruction, full 128-B lines -- into WAVE-PRIVATE
// double-buffered LDS (no barriers; fine-grained s_waitcnt vmcnt(4)).
// LDS chunk skew (+8 dwords per 8-row chunk) -> ds_read chains hit each
// bank exactly 2x (free, m136).

constexpr int kB    = 512;
constexpr int kL    = 2048;
constexpr int kD    = 32;
constexpr int kOut  = 528;           // 32 level1 + 496 areas
constexpr int kPan  = 32;            // rows per K=32 MFMA panel
constexpr int kTw   = 256;           // rows per wave
constexpr int kNP   = kTw / kPan;    // 8 panels per wave
constexpr int kCS   = 264;           // LDS dwords per 8-row chunk (256 + 8 skew)
constexpr int kBuf  = 4 * kCS;       // 1056 dwords per panel buffer

typedef __attribute__((ext_vector_type(8))) short bfrag;
typedef __attribute__((ext_vector_type(4))) float f4acc;
union FragU { uint32_t u[4]; bfrag f; };

#if defined(__has_builtin)
#if __has_builtin(__builtin_amdgcn_global_load_lds)
#define LOGSIG_ASYNC_LDS 1
#endif
#endif

__global__ __launch_bounds__(256, 4)
void logsig_mfma(const float* __restrict__ x, float* __restrict__ out) {
    __shared__ __align__(16) uint32_t sStage[4][2][kBuf];   // ~33.8 KB
    __shared__ float sx0[kD], sL1[kD];

    const int b     = blockIdx.x >> 1;
    const int chunk = blockIdx.x & 1;
    const int tid   = threadIdx.x;
    const int wave  = tid >> 6;
    const int lane  = tid & 63;
    const int m     = lane & 15;   // MFMA m/n index
    const int q     = lane >> 4;   // quad: k = q*8 + j

    const float* __restrict__ xb = x + (size_t)b * (kL * kD);
    const int t0w = chunk * 1024 + wave * kTw;   // wave's first row

    // ---- staging: 32 rows (4 chunks x 8 rows) per panel, wave-private ----
    auto stage_panel = [&](int p, int nb) {
        uint32_t* dst = &sStage[wave][nb][0];
        const uint32_t* src = (const uint32_t*)xb + (size_t)(t0w + p * kPan) * kD;
        #pragma unroll
        for (int c = 0; c < 4; ++c) {
            const uint32_t* g = src + c * 256 + lane * 4;   // 16 B per lane
            uint32_t* l = dst + c * kCS;
#ifdef LOGSIG_ASYNC_LDS
            auto* gp = reinterpret_cast<const __attribute__((address_space(1))) uint32_t*>(
                reinterpret_cast<uintptr_t>(g));
            auto* lp = reinterpret_cast<__attribute__((address_space(3))) uint32_t*>(
                reinterpret_cast<uintptr_t>(l));
            __builtin_amdgcn_global_load_lds(gp, lp, 16, 0, 0);
#else
            const float4 v = *(const float4*)g;
            *(float4*)(l + lane * 4) = v;
#endif
        }
    };

    f4acc acc[4];
    #pragma unroll
    for (int t = 0; t < 4; ++t)
        #pragma unroll
        for (int e = 0; e < 4; ++e) acc[t][e] = 0.0f;

    // hi/lo truncation split + perm-pack: A pairs (j,j+1), B pairs (j+1,j+2)
    auto make_frags = [&](const uint32_t* e, FragU& AH, FragU& AL,
                          FragU& BH, FragU& BL) {
        uint32_t l[9];
        #pragma unroll
        for (int j = 0; j < 9; ++j) {
            const uint32_t fh = e[j] & 0xffff0000u;
            const float r = __builtin_bit_cast(float, e[j])
                          - __builtin_bit_cast(float, fh);
            l[j] = __builtin_bit_cast(uint32_t, r);
        }
        #pragma unroll
        for (int d = 0; d < 4; ++d) {
            AH.u[d] = __builtin_amdgcn_perm(e[2*d+1], e[2*d],   0x07060302u);
            AL.u[d] = __builtin_amdgcn_perm(l[2*d+1], l[2*d],   0x07060302u);
            BH.u[d] = __builtin_amdgcn_perm(e[2*d+2], e[2*d+1], 0x07060302u);
            BL.u[d] = __builtin_amdgcn_perm(l[2*d+2], l[2*d+1], 0x07060302u);
        }
    };

    stage_panel(0, 0);

    #pragma unroll 2
    for (int p = 0; p < kNP; ++p) {
        const int cu = p & 1, nb = cu ^ 1;

        // halo (j=8) for q==3 lanes: clamped global dword loads (tiny)
        uint32_t h0 = 0, h1 = 0;
        if (q == 3) {
            int hr = t0w + p * kPan + 32;
            hr = hr < kL - 1 ? hr : kL - 1;
            const uint32_t* g = (const uint32_t*)xb + (size_t)hr * kD + m;
            h0 = g[0];
            h1 = g[16];
        }

        if (p + 1 < kNP) {
            stage_panel(p + 1, nb);
            asm volatile("s_waitcnt vmcnt(4)" ::: "memory");  // cur panel ready
        } else {
            asm volatile("s_waitcnt vmcnt(0)" ::: "memory");
        }

        const uint32_t* sb = &sStage[wave][cu][0];
        uint32_t e0[9], e1[9];
        #pragma unroll
        for (int j = 0; j < 8; ++j) {
            const int a = q * kCS + j * 32 + m;    // bank (8q+m)%32: 2-way, free
            e0[j] = sb[a];
            e1[j] = sb[a + 16];
        }
        {   // j=8: q<3 -> chunk q+1 row 0 (same buffer); q==3 -> global halo
            const int a = (q < 3 ? (q + 1) * kCS + m : 3 * kCS + 7 * 32 + m);
            const uint32_t d0 = sb[a], d1 = sb[a + 16];
            e0[8] = (q < 3) ? d0 : h0;
            e1[8] = (q < 3) ? d1 : h1;
        }

        FragU A0H, A0L, B0H, B0L, A1H, A1L, B1H, B1L;
        make_frags(e0, A0H, A0L, B0H, B0L);
        make_frags(e1, A1H, A1L, B1H, B1L);

        acc[0] = __builtin_amdgcn_mfma_f32_16x16x32_bf16(A0H.f, B0H.f, acc[0], 0, 0, 0);
        acc[0] = __builtin_amdgcn_mfma_f32_16x16x32_bf16(A0H.f, B0L.f, acc[0], 0, 0, 0);
        acc[0] = __builtin_amdgcn_mfma_f32_16x16x32_bf16(A0L.f, B0H.f, acc[0], 0, 0, 0);
        acc[1] = __builtin_amdgcn_mfma_f32_16x16x32_bf16(A0H.f, B1H.f, acc[1], 0, 0, 0);
        acc[1] = __builtin_amdgcn_mfma_f32_16x16x32_bf16(A0H.f, B1L.f, acc[1], 0, 0, 0);
        acc[1] = __builtin_amdgcn_mfma_f32_16x16x32_bf16(A0L.f, B1H.f, acc[1], 0, 0, 0);
        acc[2] = __builtin_amdgcn_mfma_f32_16x16x32_bf16(A1H.f, B0H.f, acc[2], 0, 0, 0);
        acc[2] = __builtin_amdgcn_mfma_f32_16x16x32_bf16(A1H.f, B0L.f, acc[2], 0, 0, 0);
        acc[2] = __builtin_amdgcn_mfma_f32_16x16x32_bf16(A1L.f, B0H.f, acc[2], 0, 0, 0);
        acc[3] = __builtin_amdgcn_mfma_f32_16x16x32_bf16(A1H.f, B1H.f, acc[3], 0, 0, 0);
        acc[3] = __builtin_amdgcn_mfma_f32_16x16x32_bf16(A1H.f, B1L.f, acc[3], 0, 0, 0);
        acc[3] = __builtin_amdgcn_mfma_f32_16x16x32_bf16(A1L.f, B1H.f, acc[3], 0, 0, 0);
    }

    // ---- epilogue: overlay per-wave M on the (now dead) stage buffers ----
    float* sWw = (float*)&sStage[wave][0][0];     // 1024 floats, wave-private
    #pragma unroll
    for (int t = 0; t < 4; ++t) {
        const int tr = t >> 1, tc = t & 1;
        #pragma unroll
        for (int e = 0; e < 4; ++e) {
            const int row = 16 * tr + q * 4 + e;  // C/D layout (m89-verified)
            const int col = 16 * tc + m;
            sWw[row * kD + col] = acc[t][e];
        }
    }
    if (tid < kD) {
        const float x0v = xb[tid];
        const float xev = xb[(size_t)(kL - 1) * kD + tid];
        sx0[tid] = x0v;
        sL1[tid] = xev - x0v;
    }
    __syncthreads();

    float* sW0 = (float*)&sStage[0][0][0];
    for (int c = tid; c < kD * kD; c += 256)
        sW0[c] += ((float*)&sStage[1][0][0])[c]
                + ((float*)&sStage[2][0][0])[c]
                + ((float*)&sStage[3][0][0])[c];
    __syncthreads();

    float* ob = out + (size_t)b * kOut;
    for (int o = tid; o < kOut; o += 256) {
        if (o < 32) {
            if (chunk == 0) ob[o] = sL1[o];        // level1, single writer
        } else {
            int p = o - 32, i = 0;                 // triu pair index -> (i,j)
            while (p >= 31 - i) { p -= 31 - i; ++i; }
            const int j = i + 1 + p;
            float v = 0.5f * (sW0[i * kD + j] - sW0[j * kD + i]);
            if (chunk == 0)
                v += 0.5f * (sx0[j] * sL1[i] - sx0[i] * sL1[j]);
            atomicAdd(ob + o, v);
        }
    }
}

extern "C" void kernel_launch(void* const* d_in, const int* in_sizes, int n_in,
                              void* d_out, int out_size, void* d_ws, size_t ws_size,
                              hipStream_t stream) {
    const float* x = (const float*)d_in[0];
    float* out = (float*)d_out;
    hipMemsetAsync(out, 0, (size_t)out_size * sizeof(float), stream);
    logsig_mfma<<<dim3(kB * 2), dim3(256), 0, stream>>>(x, out);
}